// Round 17
// baseline (291.908 us; speedup 1.0000x reference)
//
#include <hip/hip_runtime.h>
#include <cstdint>
#include <cstddef>

#define NN 100000
#define NE 1600000
#define IND 500
#define HD 64
#define OD 40
#define NBLK ((NN + 255) / 256)   // 391 scan blocks
#define KSTEPS 16                 // ceil(500/32)
#define NTT 16                    // k-tiles (BK=32)
#define EB 1563                   // ceil((NE/4)/256) = ceil(NN/64)

typedef __attribute__((ext_vector_type(8))) short short8v;
typedef __attribute__((ext_vector_type(8))) __bf16 bf16x8;
typedef __attribute__((ext_vector_type(4))) float float4v;

template <class V>
static __device__ __forceinline__ auto mfma_bf16_(V a, V b, float4v c, int)
    -> decltype(__builtin_amdgcn_mfma_f32_16x16x32_bf16(a, b, c, 0, 0, 0)) {
    return __builtin_amdgcn_mfma_f32_16x16x32_bf16(a, b, c, 0, 0, 0);
}
template <class V>
static __device__ __forceinline__ float4v mfma_bf16_(V a, V b, float4v c, long) {
    return __builtin_amdgcn_mfma_f32_16x16x32_bf16((bf16x8)a, (bf16x8)b, c, 0, 0, 0);
}
static __device__ __forceinline__ float4v mfma16(short8v a, short8v b, float4v c) {
    return mfma_bf16_(a, b, c, 0);
}

static __device__ __forceinline__ float bf2f(unsigned short v) {
    return __uint_as_float((unsigned)v << 16);
}
static __device__ __forceinline__ unsigned short f2bf(float v) {
    unsigned u = __float_as_uint(v);
    return (unsigned short)((u + 0x7fffu + ((u >> 16) & 1u)) >> 16);
}

// global -> LDS DMA, 16B per lane; dest = wave-uniform base + lane*16
typedef __attribute__((address_space(3))) char lds_char;
typedef const __attribute__((address_space(1))) char g_char;
static __device__ __forceinline__ void gl16(const char* g, char* l) {
    __builtin_amdgcn_global_load_lds((g_char*)g, (lds_char*)l, 16, 0, 0);
}

// int32 vs int64 edge dtype: 8 uniform scalar loads, no cross-kernel flag
static __device__ __forceinline__ int detect64(const void* ei) {
    const unsigned* u = (const unsigned*)ei;
    int is64 = 1;
    #pragma unroll
    for (int i = 1; i < 16; i += 2)
        if (u[i] != 0u) is64 = 0;
    return is64;
}

// load 4 consecutive edge entries starting at element index base (base % 4 == 0)
static __device__ __forceinline__ void load4e(const void* ei, int is64, size_t base, int v[4]) {
    if (is64) {
        int4 a = ((const int4*)ei)[base >> 1];
        int4 b = ((const int4*)ei)[(base >> 1) + 1];
        v[0] = a.x; v[1] = a.z; v[2] = b.x; v[3] = b.z;
    } else {
        int4 a = *(const int4*)((const int*)ei + base);
        v[0] = a.x; v[1] = a.y; v[2] = a.z; v[3] = a.w;
    }
}

// ---------- degree histogram + per-edge rank + W1 prep (fused) ----------
__global__ __launch_bounds__(256) void k_count_prep(const void* ei, int* cnt,
                                                    int* __restrict__ rank,
                                                    const float* __restrict__ W1,
                                                    unsigned short* __restrict__ wh,
                                                    unsigned short* __restrict__ wl) {
    const int is64 = detect64(ei);
    int e0 = (blockIdx.x * 256 + threadIdx.x) * 4;
    if (e0 < NE) {
        int d[4];
        load4e(ei, is64, (size_t)NE + e0, d);
        int4 r;
        r.x = atomicAdd(&cnt[d[0]], 1);
        r.y = atomicAdd(&cnt[d[1]], 1);
        r.z = atomicAdd(&cnt[d[2]], 1);
        r.w = atomicAdd(&cnt[d[3]], 1);
        *(int4*)(rank + e0) = r;
    }
    int t = blockIdx.x * 256 + threadIdx.x;
    // W1 pack: frag t = (s*4+f)*64+lane; n = f*16+(lane&15), k = s*32+8*(lane>>4)+j
    if (t < KSTEPS * 4 * 64) {
        int l = t & 63;
        int f = (t >> 6) & 3;
        int s = t >> 8;
        int n = f * 16 + (l & 15);
        int kbase = s * 32 + 8 * (l >> 4);
        unsigned short* ph = wh + (size_t)t * 8;
        unsigned short* pl = wl + (size_t)t * 8;
        #pragma unroll
        for (int j = 0; j < 8; ++j) {
            int k = kbase + j;
            float v = (k < IND) ? W1[(size_t)k * HD + n] : 0.f;
            unsigned u = __float_as_uint(v);
            ph[j] = (unsigned short)(u >> 16);                 // trunc hi
            float r = v - __uint_as_float(u & 0xffff0000u);
            pl[j] = f2bf(r);                                   // RNE lo
        }
    }
}

// ---------- exclusive scan (2 kernels); dinv fused; rowptr left PARTIAL ----------
// consumers add bsum[i>>8] on the fly (k_scan_add eliminated).
__global__ __launch_bounds__(256) void k_scan_block(const int* __restrict__ cnt,
                                                    int* __restrict__ rowptr,
                                                    int* __restrict__ bsum,
                                                    float* __restrict__ dinv) {
    int t = threadIdx.x;
    int i = blockIdx.x * 256 + t;
    int v = (i < NN) ? cnt[i] : 0;
    if (i < NN) dinv[i] = rsqrtf((float)v + 1.0f);   // +1 = self loop
    int inc = v;
    #pragma unroll
    for (int off = 1; off < 64; off <<= 1) {
        int u = __shfl_up(inc, off);
        if ((t & 63) >= off) inc += u;
    }
    __shared__ int wsum[4];
    if ((t & 63) == 63) wsum[t >> 6] = inc;
    __syncthreads();
    if (t == 0) {
        int a = 0;
        #pragma unroll
        for (int w = 0; w < 4; ++w) { int b = wsum[w]; wsum[w] = a; a += b; }
        bsum[blockIdx.x] = a;
    }
    __syncthreads();
    if (i <= NN) rowptr[i] = inc - v + wsum[t >> 6];   // i==NN: partial end sentinel
}

__global__ __launch_bounds__(512) void k_scan_bsum(int* bsum) {
    int t = threadIdx.x;
    int v = (t < NBLK) ? bsum[t] : 0;
    int inc = v;
    #pragma unroll
    for (int off = 1; off < 64; off <<= 1) {
        int u = __shfl_up(inc, off);
        if ((t & 63) >= off) inc += u;
    }
    __shared__ int wsum[8];
    if ((t & 63) == 63) wsum[t >> 6] = inc;
    __syncthreads();
    if (t == 0) {
        int a = 0;
        #pragma unroll
        for (int w = 0; w < 8; ++w) { int b = wsum[w]; wsum[w] = a; a += b; }
    }
    __syncthreads();
    if (t < NBLK) bsum[t] = inc - v + wsum[t >> 6];
}

// ---------- counting-sort scatter (pos = rp[d] + bsum[d>>8] + rank[e]) ----------
__global__ void k_scatter(const void* ei, const int* __restrict__ rp,
                          const int* __restrict__ bs,
                          const int* __restrict__ rank, int* __restrict__ srcs) {
    int e0 = (blockIdx.x * 256 + threadIdx.x) * 4;
    if (e0 >= NE) return;
    const int is64 = detect64(ei);
    int s[4], d[4];
    load4e(ei, is64, (size_t)e0, s);
    load4e(ei, is64, (size_t)NE + e0, d);
    int4 r = *(const int4*)(rank + e0);
    srcs[rp[d[0]] + bs[d[0] >> 8] + r.x] = s[0];
    srcs[rp[d[1]] + bs[d[1] >> 8] + r.y] = s[1];
    srcs[rp[d[2]] + bs[d[2] >> 8] + r.z] = s[2];
    srcs[rp[d[3]] + bs[d[3] >> 8] + r.w] = s[3];
}

// ---------- GEMM1: MFMA + global_load_lds; BK=32, 2 bufs (32KB), 5 blocks/CU,
// counted vmcnt(4) + dual barrier: stage(t+1) stays in flight across compute(t).
static __device__ __forceinline__ void split8f(float4 u0, float4 u1,
                                               short8v& hi, short8v& lo) {
    float t[8] = {u0.x, u0.y, u0.z, u0.w, u1.x, u1.y, u1.z, u1.w};
    #pragma unroll
    for (int j = 0; j < 8; ++j) {
        unsigned q = __float_as_uint(t[j]);
        hi[j] = (short)(q >> 16);
        float r = t[j] - __uint_as_float(q & 0xffff0000u);
        lo[j] = (short)f2bf(r);
    }
}

__global__ __launch_bounds__(256, 5) void k_gemm1m(const float* __restrict__ x,
                                                   const char* __restrict__ whb,
                                                   const char* __restrict__ wlb,
                                                   const float* __restrict__ dinv,
                                                   unsigned short* __restrict__ h) {
    __shared__ char smem[32768];   // 2 bufs x (A 8KB + B 8KB)
    const int tid  = threadIdx.x;
    const int lane = tid & 63;
    const int wave = tid >> 6;
    const int row0 = blockIdx.x * 64;
    const int rA = lane & 15;
    const int cg = lane >> 4;

    auto stage = [&](int kt, int buf) {
        const bool tail = (kt == NTT - 1);
        #pragma unroll
        for (int i = 0; i < 2; ++i) {           // A: 512 slots (64 rows x 8 chunks)
            int slot = i * 256 + tid;
            int r = slot >> 3, c = slot & 7;
            int cs = c ^ (r & 7);               // pre-swizzled source chunk (3-bit bijection)
            if (tail && cs > 4) cs = 4;         // clamp: finite dup data * W-pad(0) = 0
            int rsrc = row0 + r; if (rsrc >= NN) rsrc = NN - 1;
            const char* g = (const char*)x + (size_t)rsrc * (IND * 4) + kt * 128 + cs * 16;
            char* l = smem + buf * 16384 + (i * 256 + wave * 64) * 16;
            gl16(g, l);
        }
        #pragma unroll
        for (int i = 0; i < 2; ++i) {           // B: wh 256 slots + wl 256 slots, linear
            int j = i * 256 + tid;
            const char* src = (j < 256 ? whb : wlb) + kt * 4096 + (size_t)(j & 255) * 16;
            char* l = smem + buf * 16384 + 8192 + (i * 256 + wave * 64) * 16;
            gl16(src, l);
        }
    };

    float4v acc[4];
    const float4v zero4 = {0.f, 0.f, 0.f, 0.f};
    #pragma unroll
    for (int f = 0; f < 4; ++f) acc[f] = zero4;

    stage(0, 0);
    stage(1, 1);

    const int rbase = (wave * 16 + rA) * 8;
    const int sw = rA & 7;

    for (int kt = 0; kt < NTT; ++kt) {
        // wait ONLY for tile kt's 4 loads; tile kt+1 stays in flight.
        if (kt + 1 < NTT) asm volatile("s_waitcnt vmcnt(4)\ns_barrier" ::: "memory");
        else              asm volatile("s_waitcnt vmcnt(0)\ns_barrier" ::: "memory");
        const float4*  pa = (const float4*)(smem + (kt & 1) * 16384);
        const short8v* pb = (const short8v*)(smem + (kt & 1) * 16384 + 8192);
        int ch = cg * 2;
        float4 u0 = pa[rbase + (ch ^ sw)];
        float4 u1 = pa[rbase + ((ch + 1) ^ sw)];
        short8v ah, al;
        split8f(u0, u1, ah, al);
        #pragma unroll
        for (int f = 0; f < 4; ++f) {
            short8v vh = pb[f * 64 + lane];
            short8v vl = pb[256 + f * 64 + lane];
            acc[f] = mfma16(al, vh, acc[f]);
            acc[f] = mfma16(ah, vl, acc[f]);
            acc[f] = mfma16(ah, vh, acc[f]);
        }
        if (kt + 2 < NTT) {
            // all waves done reading buf (kt&1), then restage it for tile kt+2.
            asm volatile("s_barrier" ::: "memory");
            stage(kt + 2, kt & 1);
        }
    }

    // C/D layout (m89-verified): col = lane&15, row = (lane>>4)*4 + reg
    #pragma unroll
    for (int j = 0; j < 4; ++j) {
        int row = row0 + wave * 16 + cg * 4 + j;
        if (row < NN) {
            float dv = dinv[row];
            #pragma unroll
            for (int f = 0; f < 4; ++f)
                h[(size_t)row * HD + f * 16 + rA] = f2bf(acc[f][j] * dv);
        }
    }
}

// ---------- layer-1 agg + fused 64->40 projection ----------
// per wave: hs2 = dinv*relu(dn*sum + b1) (fp32, one value/lane) -> LDS ->
// lanes<40 dot with fp32 W2 -> pb[node][40] bf16. hrelub never materialized.
__global__ __launch_bounds__(256) void k_agg1proj(const int* __restrict__ rp,
                                                  const int* __restrict__ bs,
                                                  const int* __restrict__ srcs,
                                                  const float* __restrict__ dinv,
                                                  const unsigned short* __restrict__ hb,
                                                  const float* __restrict__ bias,
                                                  const float* __restrict__ W2,
                                                  unsigned short* __restrict__ pb) {
    __shared__ float ws2[HD][OD];   // 10.24 KB
    __shared__ float hsh[4][HD];    // 1 KB
    const int t = threadIdx.x;
    for (int i = t; i < HD * OD; i += 256)
        ws2[i / OD][i % OD] = W2[i];

    int wid = (blockIdx.x * 256 + t) >> 6;      // grid covers NN exactly
    int lane = t & 63;
    int w = t >> 6;
    float acc = bf2f(hb[(size_t)wid * HD + lane]);   // self loop (hs already dinv-scaled)
    int beg = rp[wid] + bs[wid >> 8];
    int cnt = rp[wid + 1] + bs[(wid + 1) >> 8] - beg;
    for (int base = 0; base < cnt; base += 64) {
        int m = cnt - base; if (m > 64) m = 64;
        int sj = (lane < m) ? srcs[beg + base + lane] : 0;
        int j = 0;
        for (; j + 8 <= m; j += 8) {
            int s0 = __builtin_amdgcn_readlane(sj, j);
            int s1 = __builtin_amdgcn_readlane(sj, j + 1);
            int s2 = __builtin_amdgcn_readlane(sj, j + 2);
            int s3 = __builtin_amdgcn_readlane(sj, j + 3);
            int s4 = __builtin_amdgcn_readlane(sj, j + 4);
            int s5 = __builtin_amdgcn_readlane(sj, j + 5);
            int s6 = __builtin_amdgcn_readlane(sj, j + 6);
            int s7 = __builtin_amdgcn_readlane(sj, j + 7);
            float v0 = bf2f(hb[(size_t)s0 * HD + lane]);
            float v1 = bf2f(hb[(size_t)s1 * HD + lane]);
            float v2 = bf2f(hb[(size_t)s2 * HD + lane]);
            float v3 = bf2f(hb[(size_t)s3 * HD + lane]);
            float v4 = bf2f(hb[(size_t)s4 * HD + lane]);
            float v5 = bf2f(hb[(size_t)s5 * HD + lane]);
            float v6 = bf2f(hb[(size_t)s6 * HD + lane]);
            float v7 = bf2f(hb[(size_t)s7 * HD + lane]);
            acc += ((v0 + v1) + (v2 + v3)) + ((v4 + v5) + (v6 + v7));
        }
        for (; j < m; ++j) {
            int s = __builtin_amdgcn_readlane(sj, j);
            acc += bf2f(hb[(size_t)s * HD + lane]);
        }
    }
    float dn = dinv[wid];
    hsh[w][lane] = fmaxf(acc * dn + bias[lane], 0.f) * dn;   // hs2 row, fp32
    __syncthreads();   // ws2 loaded + hsh visible
    if (lane < OD) {
        float s = 0.f;
        #pragma unroll
        for (int k = 0; k < HD; ++k)
            s = fmaf(hsh[w][k], ws2[k][lane], s);
        pb[(size_t)wid * OD + lane] = f2bf(s);
    }
}

// ---------- layer-2 aggregation in 40-dim: out = dn * sum(p) + b2 ----------
__global__ __launch_bounds__(256) void k_agg2(const int* __restrict__ rp,
                                              const int* __restrict__ bs,
                                              const int* __restrict__ srcs,
                                              const float* __restrict__ dinv,
                                              const unsigned short* __restrict__ pb,
                                              const float* __restrict__ b2,
                                              float* __restrict__ out) {
    int wid = (blockIdx.x * 256 + threadIdx.x) >> 6;
    int lane = threadIdx.x & 63;
    if (wid >= NN) return;
    // lanes >= OD compute garbage partial sums, never stored (pb region fully written).
    float acc = bf2f(pb[(size_t)wid * OD + lane]);   // self loop (p carries source dinv)
    int beg = rp[wid] + bs[wid >> 8];
    int cnt = rp[wid + 1] + bs[(wid + 1) >> 8] - beg;
    for (int base = 0; base < cnt; base += 64) {
        int m = cnt - base; if (m > 64) m = 64;
        int sj = (lane < m) ? srcs[beg + base + lane] : 0;
        int j = 0;
        for (; j + 8 <= m; j += 8) {
            int s0 = __builtin_amdgcn_readlane(sj, j);
            int s1 = __builtin_amdgcn_readlane(sj, j + 1);
            int s2 = __builtin_amdgcn_readlane(sj, j + 2);
            int s3 = __builtin_amdgcn_readlane(sj, j + 3);
            int s4 = __builtin_amdgcn_readlane(sj, j + 4);
            int s5 = __builtin_amdgcn_readlane(sj, j + 5);
            int s6 = __builtin_amdgcn_readlane(sj, j + 6);
            int s7 = __builtin_amdgcn_readlane(sj, j + 7);
            float v0 = bf2f(pb[(size_t)s0 * OD + lane]);
            float v1 = bf2f(pb[(size_t)s1 * OD + lane]);
            float v2 = bf2f(pb[(size_t)s2 * OD + lane]);
            float v3 = bf2f(pb[(size_t)s3 * OD + lane]);
            float v4 = bf2f(pb[(size_t)s4 * OD + lane]);
            float v5 = bf2f(pb[(size_t)s5 * OD + lane]);
            float v6 = bf2f(pb[(size_t)s6 * OD + lane]);
            float v7 = bf2f(pb[(size_t)s7 * OD + lane]);
            acc += ((v0 + v1) + (v2 + v3)) + ((v4 + v5) + (v6 + v7));
        }
        for (; j < m; ++j) {
            int s = __builtin_amdgcn_readlane(sj, j);
            acc += bf2f(pb[(size_t)s * OD + lane]);
        }
    }
    if (lane < OD)
        out[(size_t)wid * OD + lane] = acc * dinv[wid] + b2[lane];
}

extern "C" void kernel_launch(void* const* d_in, const int* in_sizes, int n_in,
                              void* d_out, int out_size, void* d_ws, size_t ws_size,
                              hipStream_t stream) {
    const float* x  = (const float*)d_in[0];
    const float* W1 = (const float*)d_in[1];
    const float* b1 = (const float*)d_in[2];
    const float* W2 = (const float*)d_in[3];
    const float* b2 = (const float*)d_in[4];
    const void*  ei = d_in[5];
    float* out = (float*)d_out;

    // --- all scratch in d_ws (d_out written only by the final kernel) ---
    char* ws = (char*)d_ws;
    unsigned short* h1b   = (unsigned short*)ws;                     // 12,800,000
    unsigned short* pb    = (unsigned short*)(ws + 12800000);        // 8,000,000 (separate: agg1proj reads h1b while writing pb)
    int*   rowptr = (int*)(ws + 25600000);                           // 400,896
    int*   cnt    = (int*)(ws + 26000896);                           // 400,896
    int*   bsum   = (int*)(ws + 26401792);                           // 2,048
    int*   srcs   = (int*)(ws + 26403840);                           // 6,400,000
    int*   rank   = (int*)(ws + 32803840);                           // 6,400,000
    float* dinv   = (float*)(ws + 39203840);                         // 400,384
    unsigned short* wh  = (unsigned short*)(ws + 39604224);          // 65,536
    unsigned short* wl  = (unsigned short*)(ws + 39669760);          // 65,536 (end 39,735,296)

    // 1. zero degree counters
    hipMemsetAsync(cnt, 0, (size_t)NN * 4, stream);
    // 2. degree histogram + rank + W1 pack
    k_count_prep<<<EB, 256, 0, stream>>>(ei, cnt, rank, W1, wh, wl);
    // 3-4. exclusive scan (+dinv); rowptr stays partial, consumers add bsum
    k_scan_block<<<NBLK, 256, 0, stream>>>(cnt, rowptr, bsum, dinv);
    k_scan_bsum<<<1, 512, 0, stream>>>(bsum);
    // 5. edge scatter (atomic-free)
    k_scatter<<<EB, 256, 0, stream>>>(ei, rowptr, bsum, rank, srcs);
    // 6. GEMM1 (counted-vmcnt pipelined MFMA, 5 blocks/CU)
    k_gemm1m<<<EB, 256, 0, stream>>>(x, (const char*)wh, (const char*)wl, dinv, h1b);
    // 7. layer-1 aggregation + bias + relu + fused 64->40 projection
    k_agg1proj<<<(NN * 64) / 256, 256, 0, stream>>>(rowptr, bsum, srcs, dinv, h1b, b1, W2, pb);
    // 8. layer-2 aggregation in 40-dim, straight to d_out
    k_agg2<<<(NN * 64) / 256, 256, 0, stream>>>(rowptr, bsum, srcs, dinv, pb, b2, out);
}

// Round 18
// 263.403 us; speedup vs baseline: 1.1082x; 1.1082x over previous
//
#include <hip/hip_runtime.h>
#include <cstdint>
#include <cstddef>

#define NN 100000
#define NE 1600000
#define IND 500
#define HD 64
#define OD 40
#define NBLK ((NN + 255) / 256)   // 391 scan blocks
#define KSTEPS 16                 // ceil(500/32)
#define NTT 16                    // k-tiles (BK=32)
#define EB 1563                   // ceil((NE/4)/256) = ceil(NN/64)

typedef __attribute__((ext_vector_type(8))) short short8v;
typedef __attribute__((ext_vector_type(8))) __bf16 bf16x8;
typedef __attribute__((ext_vector_type(4))) float float4v;

template <class V>
static __device__ __forceinline__ auto mfma_bf16_(V a, V b, float4v c, int)
    -> decltype(__builtin_amdgcn_mfma_f32_16x16x32_bf16(a, b, c, 0, 0, 0)) {
    return __builtin_amdgcn_mfma_f32_16x16x32_bf16(a, b, c, 0, 0, 0);
}
template <class V>
static __device__ __forceinline__ float4v mfma_bf16_(V a, V b, float4v c, long) {
    return __builtin_amdgcn_mfma_f32_16x16x32_bf16((bf16x8)a, (bf16x8)b, c, 0, 0, 0);
}
static __device__ __forceinline__ float4v mfma16(short8v a, short8v b, float4v c) {
    return mfma_bf16_(a, b, c, 0);
}

static __device__ __forceinline__ float bf2f(unsigned short v) {
    return __uint_as_float((unsigned)v << 16);
}
static __device__ __forceinline__ unsigned short f2bf(float v) {
    unsigned u = __float_as_uint(v);
    return (unsigned short)((u + 0x7fffu + ((u >> 16) & 1u)) >> 16);
}

// global -> LDS DMA, 16B per lane; dest = wave-uniform base + lane*16
typedef __attribute__((address_space(3))) char lds_char;
typedef const __attribute__((address_space(1))) char g_char;
static __device__ __forceinline__ void gl16(const char* g, char* l) {
    __builtin_amdgcn_global_load_lds((g_char*)g, (lds_char*)l, 16, 0, 0);
}

// int32 vs int64 edge dtype: 8 uniform scalar loads, no cross-kernel flag
static __device__ __forceinline__ int detect64(const void* ei) {
    const unsigned* u = (const unsigned*)ei;
    int is64 = 1;
    #pragma unroll
    for (int i = 1; i < 16; i += 2)
        if (u[i] != 0u) is64 = 0;
    return is64;
}

// load 4 consecutive edge entries starting at element index base (base % 4 == 0)
static __device__ __forceinline__ void load4e(const void* ei, int is64, size_t base, int v[4]) {
    if (is64) {
        int4 a = ((const int4*)ei)[base >> 1];
        int4 b = ((const int4*)ei)[(base >> 1) + 1];
        v[0] = a.x; v[1] = a.z; v[2] = b.x; v[3] = b.z;
    } else {
        int4 a = *(const int4*)((const int*)ei + base);
        v[0] = a.x; v[1] = a.y; v[2] = a.z; v[3] = a.w;
    }
}

// ---------- zero degree counters (replaces hipMemsetAsync fillBuffer) ----------
__global__ void k_zero(int* __restrict__ cnt) {
    int i = blockIdx.x * 256 + threadIdx.x;
    if (i < NN) cnt[i] = 0;
}

// ---------- degree histogram + per-edge rank + W1/W2 prep (fused) ----------
__global__ __launch_bounds__(256) void k_count_prep(const void* ei, int* cnt,
                                                    int* __restrict__ rank,
                                                    const float* __restrict__ W1,
                                                    unsigned short* __restrict__ wh,
                                                    unsigned short* __restrict__ wl,
                                                    const float* __restrict__ W2,
                                                    unsigned short* __restrict__ wh2,
                                                    unsigned short* __restrict__ wl2) {
    const int is64 = detect64(ei);
    int e0 = (blockIdx.x * 256 + threadIdx.x) * 4;
    if (e0 < NE) {
        int d[4];
        load4e(ei, is64, (size_t)NE + e0, d);
        int4 r;
        r.x = atomicAdd(&cnt[d[0]], 1);
        r.y = atomicAdd(&cnt[d[1]], 1);
        r.z = atomicAdd(&cnt[d[2]], 1);
        r.w = atomicAdd(&cnt[d[3]], 1);
        *(int4*)(rank + e0) = r;
    }
    int t = blockIdx.x * 256 + threadIdx.x;
    // W1 pack: frag t = (s*4+f)*64+lane; n = f*16+(lane&15), k = s*32+8*(lane>>4)+j
    if (t < KSTEPS * 4 * 64) {
        int l = t & 63;
        int f = (t >> 6) & 3;
        int s = t >> 8;
        int n = f * 16 + (l & 15);
        int kbase = s * 32 + 8 * (l >> 4);
        unsigned short* ph = wh + (size_t)t * 8;
        unsigned short* pl = wl + (size_t)t * 8;
        #pragma unroll
        for (int j = 0; j < 8; ++j) {
            int k = kbase + j;
            float v = (k < IND) ? W1[(size_t)k * HD + n] : 0.f;
            unsigned u = __float_as_uint(v);
            ph[j] = (unsigned short)(u >> 16);                 // trunc hi
            float r = v - __uint_as_float(u & 0xffff0000u);
            pl[j] = f2bf(r);                                   // RNE lo
        }
    }
    // W2 pack: 2 s x 3 f x 64 lanes; frag t2 = (s*3+f)*64+lane
    if (t >= 4096 && t < 4096 + 384) {
        int t2 = t - 4096;
        int l = t2 & 63;
        int f = (t2 >> 6) % 3;
        int s = t2 / 192;
        int n = f * 16 + (l & 15);                             // [0,48)
        int kbase = s * 32 + 8 * (l >> 4);                     // k < 64 always
        unsigned short* ph = wh2 + (size_t)t2 * 8;
        unsigned short* pl = wl2 + (size_t)t2 * 8;
        #pragma unroll
        for (int j = 0; j < 8; ++j) {
            int k = kbase + j;
            float v = (n < OD) ? W2[(size_t)k * OD + n] : 0.f;
            unsigned u = __float_as_uint(v);
            ph[j] = (unsigned short)(u >> 16);
            float r = v - __uint_as_float(u & 0xffff0000u);
            pl[j] = f2bf(r);
        }
    }
}

// ---------- exclusive scan (3 kernels); dinv fused into pass 1 ----------
__global__ __launch_bounds__(256) void k_scan_block(const int* __restrict__ cnt,
                                                    int* __restrict__ rowptr,
                                                    int* __restrict__ bsum,
                                                    float* __restrict__ dinv) {
    int t = threadIdx.x;
    int i = blockIdx.x * 256 + t;
    int v = (i < NN) ? cnt[i] : 0;
    if (i < NN) dinv[i] = rsqrtf((float)v + 1.0f);   // +1 = self loop
    int inc = v;
    #pragma unroll
    for (int off = 1; off < 64; off <<= 1) {
        int u = __shfl_up(inc, off);
        if ((t & 63) >= off) inc += u;
    }
    __shared__ int wsum[4];
    if ((t & 63) == 63) wsum[t >> 6] = inc;
    __syncthreads();
    if (t == 0) {
        int a = 0;
        #pragma unroll
        for (int w = 0; w < 4; ++w) { int b = wsum[w]; wsum[w] = a; a += b; }
        bsum[blockIdx.x] = a;
    }
    __syncthreads();
    if (i < NN) rowptr[i] = inc - v + wsum[t >> 6];
}

__global__ __launch_bounds__(512) void k_scan_bsum(int* bsum) {
    int t = threadIdx.x;
    int v = (t < NBLK) ? bsum[t] : 0;
    int inc = v;
    #pragma unroll
    for (int off = 1; off < 64; off <<= 1) {
        int u = __shfl_up(inc, off);
        if ((t & 63) >= off) inc += u;
    }
    __shared__ int wsum[8];
    if ((t & 63) == 63) wsum[t >> 6] = inc;
    __syncthreads();
    if (t == 0) {
        int a = 0;
        #pragma unroll
        for (int w = 0; w < 8; ++w) { int b = wsum[w]; wsum[w] = a; a += b; }
    }
    __syncthreads();
    if (t < NBLK) bsum[t] = inc - v + wsum[t >> 6];
}

__global__ void k_scan_add(int* rowptr, const int* __restrict__ bsum) {
    int i = blockIdx.x * 256 + threadIdx.x;
    if (i < NN) rowptr[i] += bsum[i >> 8];
    if (i == 0) rowptr[NN] = NE;
}

// ---------- counting-sort scatter (no atomics: pos = rowptr[d] + rank[e]) ----------
__global__ void k_scatter(const void* ei, const int* __restrict__ rowptr,
                          const int* __restrict__ rank, int* __restrict__ srcs) {
    int e0 = (blockIdx.x * 256 + threadIdx.x) * 4;
    if (e0 >= NE) return;
    const int is64 = detect64(ei);
    int s[4], d[4];
    load4e(ei, is64, (size_t)e0, s);
    load4e(ei, is64, (size_t)NE + e0, d);
    int4 r = *(const int4*)(rank + e0);
    srcs[rowptr[d[0]] + r.x] = s[0];
    srcs[rowptr[d[1]] + r.y] = s[1];
    srcs[rowptr[d[2]] + r.z] = s[2];
    srcs[rowptr[d[3]] + r.w] = s[3];
}

// ---------- GEMM1: MFMA + global_load_lds; BK=32, 2 bufs (32KB), 5 blocks/CU,
// counted vmcnt(4) + dual barrier: stage(t+1) stays in flight across compute(t).
static __device__ __forceinline__ void split8f(float4 u0, float4 u1,
                                               short8v& hi, short8v& lo) {
    float t[8] = {u0.x, u0.y, u0.z, u0.w, u1.x, u1.y, u1.z, u1.w};
    #pragma unroll
    for (int j = 0; j < 8; ++j) {
        unsigned q = __float_as_uint(t[j]);
        hi[j] = (short)(q >> 16);
        float r = t[j] - __uint_as_float(q & 0xffff0000u);
        lo[j] = (short)f2bf(r);
    }
}

__global__ __launch_bounds__(256, 5) void k_gemm1m(const float* __restrict__ x,
                                                   const char* __restrict__ whb,
                                                   const char* __restrict__ wlb,
                                                   const float* __restrict__ dinv,
                                                   unsigned short* __restrict__ h) {
    __shared__ char smem[32768];   // 2 bufs x (A 8KB + B 8KB)
    const int tid  = threadIdx.x;
    const int lane = tid & 63;
    const int wave = tid >> 6;
    const int row0 = blockIdx.x * 64;
    const int rA = lane & 15;
    const int cg = lane >> 4;

    auto stage = [&](int kt, int buf) {
        const bool tail = (kt == NTT - 1);
        #pragma unroll
        for (int i = 0; i < 2; ++i) {           // A: 512 slots (64 rows x 8 chunks)
            int slot = i * 256 + tid;
            int r = slot >> 3, c = slot & 7;
            int cs = c ^ (r & 7);               // pre-swizzled source chunk (3-bit bijection)
            if (tail && cs > 4) cs = 4;         // clamp: finite dup data * W-pad(0) = 0
            int rsrc = row0 + r; if (rsrc >= NN) rsrc = NN - 1;
            const char* g = (const char*)x + (size_t)rsrc * (IND * 4) + kt * 128 + cs * 16;
            char* l = smem + buf * 16384 + (i * 256 + wave * 64) * 16;
            gl16(g, l);
        }
        #pragma unroll
        for (int i = 0; i < 2; ++i) {           // B: wh 256 slots + wl 256 slots, linear
            int j = i * 256 + tid;
            const char* src = (j < 256 ? whb : wlb) + kt * 4096 + (size_t)(j & 255) * 16;
            char* l = smem + buf * 16384 + 8192 + (i * 256 + wave * 64) * 16;
            gl16(src, l);
        }
    };

    float4v acc[4];
    const float4v zero4 = {0.f, 0.f, 0.f, 0.f};
    #pragma unroll
    for (int f = 0; f < 4; ++f) acc[f] = zero4;

    stage(0, 0);
    stage(1, 1);

    const int rbase = (wave * 16 + rA) * 8;
    const int sw = rA & 7;

    for (int kt = 0; kt < NTT; ++kt) {
        // wait ONLY for tile kt's 4 loads; tile kt+1 stays in flight.
        if (kt + 1 < NTT) asm volatile("s_waitcnt vmcnt(4)\ns_barrier" ::: "memory");
        else              asm volatile("s_waitcnt vmcnt(0)\ns_barrier" ::: "memory");
        const float4*  pa = (const float4*)(smem + (kt & 1) * 16384);
        const short8v* pb = (const short8v*)(smem + (kt & 1) * 16384 + 8192);
        int ch = cg * 2;
        float4 u0 = pa[rbase + (ch ^ sw)];
        float4 u1 = pa[rbase + ((ch + 1) ^ sw)];
        short8v ah, al;
        split8f(u0, u1, ah, al);
        #pragma unroll
        for (int f = 0; f < 4; ++f) {
            short8v vh = pb[f * 64 + lane];
            short8v vl = pb[256 + f * 64 + lane];
            acc[f] = mfma16(al, vh, acc[f]);
            acc[f] = mfma16(ah, vl, acc[f]);
            acc[f] = mfma16(ah, vh, acc[f]);
        }
        if (kt + 2 < NTT) {
            // all waves done reading buf (kt&1), then restage it for tile kt+2.
            asm volatile("s_barrier" ::: "memory");
            stage(kt + 2, kt & 1);
        }
    }

    // C/D layout (m89-verified): col = lane&15, row = (lane>>4)*4 + reg
    #pragma unroll
    for (int j = 0; j < 4; ++j) {
        int row = row0 + wave * 16 + cg * 4 + j;
        if (row < NN) {
            float dv = dinv[row];
            #pragma unroll
            for (int f = 0; f < 4; ++f)
                h[(size_t)row * HD + f * 16 + rA] = f2bf(acc[f][j] * dv);
        }
    }
}

// ---------- layer-1 CSR aggregation: hs2 = bf16(dinv*relu(dn*sum + b1)) ----------
__global__ __launch_bounds__(256) void k_agg1(const int* __restrict__ rowptr,
                                              const int* __restrict__ srcs,
                                              const float* __restrict__ dinv,
                                              const unsigned short* __restrict__ hb,
                                              const float* __restrict__ bias,
                                              unsigned short* __restrict__ outb) {
    int wid = (blockIdx.x * 256 + threadIdx.x) >> 6;
    int lane = threadIdx.x & 63;
    if (wid >= NN) return;
    float acc = bf2f(hb[(size_t)wid * HD + lane]);   // self loop (hs already dinv-scaled)
    int beg = rowptr[wid];
    int cnt = rowptr[wid + 1] - beg;
    for (int base = 0; base < cnt; base += 64) {
        int m = cnt - base; if (m > 64) m = 64;
        int sj = (lane < m) ? srcs[beg + base + lane] : 0;
        int j = 0;
        for (; j + 8 <= m; j += 8) {
            int s0 = __builtin_amdgcn_readlane(sj, j);
            int s1 = __builtin_amdgcn_readlane(sj, j + 1);
            int s2 = __builtin_amdgcn_readlane(sj, j + 2);
            int s3 = __builtin_amdgcn_readlane(sj, j + 3);
            int s4 = __builtin_amdgcn_readlane(sj, j + 4);
            int s5 = __builtin_amdgcn_readlane(sj, j + 5);
            int s6 = __builtin_amdgcn_readlane(sj, j + 6);
            int s7 = __builtin_amdgcn_readlane(sj, j + 7);
            float v0 = bf2f(hb[(size_t)s0 * HD + lane]);
            float v1 = bf2f(hb[(size_t)s1 * HD + lane]);
            float v2 = bf2f(hb[(size_t)s2 * HD + lane]);
            float v3 = bf2f(hb[(size_t)s3 * HD + lane]);
            float v4 = bf2f(hb[(size_t)s4 * HD + lane]);
            float v5 = bf2f(hb[(size_t)s5 * HD + lane]);
            float v6 = bf2f(hb[(size_t)s6 * HD + lane]);
            float v7 = bf2f(hb[(size_t)s7 * HD + lane]);
            acc += ((v0 + v1) + (v2 + v3)) + ((v4 + v5) + (v6 + v7));
        }
        for (; j < m; ++j) {
            int s = __builtin_amdgcn_readlane(sj, j);
            acc += bf2f(hb[(size_t)s * HD + lane]);
        }
    }
    float dn = dinv[wid];
    outb[(size_t)wid * HD + lane] = f2bf(fmaxf(acc * dn + bias[lane], 0.f) * dn);
}

// ---------- projection: p = bf16( hrelu @ W2 ), [NN x 40] ----------
// hrelu already carries its source-side dinv (baked in by k_agg1) — no extra dinv.
__global__ __launch_bounds__(256) void k_proj(const unsigned short* __restrict__ hr,
                                              const short8v* __restrict__ wh2,
                                              const short8v* __restrict__ wl2,
                                              unsigned short* __restrict__ p) {
    const int lane = threadIdx.x & 63;
    const int wave = threadIdx.x >> 6;
    const int row0 = (blockIdx.x * 4 + wave) * 16;
    if (row0 >= NN) return;
    const int rA = lane & 15;
    const int cg = lane >> 4;
    float4v acc[3];
    const float4v zero4 = {0.f, 0.f, 0.f, 0.f};
    #pragma unroll
    for (int f = 0; f < 3; ++f) acc[f] = zero4;
    const unsigned short* ap = hr + (size_t)(row0 + rA) * HD + cg * 8;
    #pragma unroll
    for (int s = 0; s < 2; ++s) {
        short8v a = *(const short8v*)(ap + s * 32);
        #pragma unroll
        for (int f = 0; f < 3; ++f) {
            short8v vh = wh2[(s * 3 + f) * 64 + lane];
            short8v vl = wl2[(s * 3 + f) * 64 + lane];
            acc[f] = mfma16(a, vl, acc[f]);
            acc[f] = mfma16(a, vh, acc[f]);
        }
    }
    // C/D layout: col = f*16 + (lane&15), row = cg*4 + j
    #pragma unroll
    for (int j = 0; j < 4; ++j) {
        int row = row0 + cg * 4 + j;
        #pragma unroll
        for (int f = 0; f < 3; ++f) {
            int c = f * 16 + rA;
            if (c < OD)
                p[(size_t)row * OD + c] = f2bf(acc[f][j]);
        }
    }
}

// ---------- layer-2 aggregation in 40-dim: out = dn * sum(p) + b2 ----------
// lanes >= OD clamp to lane-OD so their (discarded) loads re-use lanes 0-23's
// cache lines instead of touching the next row's line.
__global__ __launch_bounds__(256) void k_agg2(const int* __restrict__ rowptr,
                                              const int* __restrict__ srcs,
                                              const float* __restrict__ dinv,
                                              const unsigned short* __restrict__ pb,
                                              const float* __restrict__ b2,
                                              float* __restrict__ out) {
    int wid = (blockIdx.x * 256 + threadIdx.x) >> 6;
    int lane = threadIdx.x & 63;
    if (wid >= NN) return;
    const int lcl = (lane < OD) ? lane : (lane - OD);   // clamp into the 80B row
    float acc = bf2f(pb[(size_t)wid * OD + lcl]);   // self loop (p carries source dinv)
    int beg = rowptr[wid];
    int cnt = rowptr[wid + 1] - beg;
    for (int base = 0; base < cnt; base += 64) {
        int m = cnt - base; if (m > 64) m = 64;
        int sj = (lane < m) ? srcs[beg + base + lane] : 0;
        int j = 0;
        for (; j + 8 <= m; j += 8) {
            int s0 = __builtin_amdgcn_readlane(sj, j);
            int s1 = __builtin_amdgcn_readlane(sj, j + 1);
            int s2 = __builtin_amdgcn_readlane(sj, j + 2);
            int s3 = __builtin_amdgcn_readlane(sj, j + 3);
            int s4 = __builtin_amdgcn_readlane(sj, j + 4);
            int s5 = __builtin_amdgcn_readlane(sj, j + 5);
            int s6 = __builtin_amdgcn_readlane(sj, j + 6);
            int s7 = __builtin_amdgcn_readlane(sj, j + 7);
            float v0 = bf2f(pb[(size_t)s0 * OD + lcl]);
            float v1 = bf2f(pb[(size_t)s1 * OD + lcl]);
            float v2 = bf2f(pb[(size_t)s2 * OD + lcl]);
            float v3 = bf2f(pb[(size_t)s3 * OD + lcl]);
            float v4 = bf2f(pb[(size_t)s4 * OD + lcl]);
            float v5 = bf2f(pb[(size_t)s5 * OD + lcl]);
            float v6 = bf2f(pb[(size_t)s6 * OD + lcl]);
            float v7 = bf2f(pb[(size_t)s7 * OD + lcl]);
            acc += ((v0 + v1) + (v2 + v3)) + ((v4 + v5) + (v6 + v7));
        }
        for (; j < m; ++j) {
            int s = __builtin_amdgcn_readlane(sj, j);
            acc += bf2f(pb[(size_t)s * OD + lcl]);
        }
    }
    if (lane < OD)
        out[(size_t)wid * OD + lane] = acc * dinv[wid] + b2[lane];
}

extern "C" void kernel_launch(void* const* d_in, const int* in_sizes, int n_in,
                              void* d_out, int out_size, void* d_ws, size_t ws_size,
                              hipStream_t stream) {
    const float* x  = (const float*)d_in[0];
    const float* W1 = (const float*)d_in[1];
    const float* b1 = (const float*)d_in[2];
    const float* W2 = (const float*)d_in[3];
    const float* b2 = (const float*)d_in[4];
    const void*  ei = d_in[5];
    float* out = (float*)d_out;

    // --- all scratch in d_ws (d_out written only by the final kernel) ---
    char* ws = (char*)d_ws;
    unsigned short* h1b    = (unsigned short*)ws;                    // 12,800,000
    unsigned short* pb     = (unsigned short*)ws;                    // alias: h1b dead after k_agg1
    unsigned short* hrelub = (unsigned short*)(ws + 12800000);       // 12,800,000
    int*   rowptr = (int*)(ws + 25600000);                           // 400,896
    int*   cnt    = (int*)(ws + 26000896);                           // 400,896
    int*   bsum   = (int*)(ws + 26401792);                           // 2,048
    int*   srcs   = (int*)(ws + 26403840);                           // 6,400,000
    int*   rank   = (int*)(ws + 32803840);                           // 6,400,000
    float* dinv   = (float*)(ws + 39203840);                         // 400,384
    unsigned short* wh  = (unsigned short*)(ws + 39604224);          // 65,536
    unsigned short* wl  = (unsigned short*)(ws + 39669760);          // 65,536
    unsigned short* wh2 = (unsigned short*)(ws + 39735296);          // 6,144
    unsigned short* wl2 = (unsigned short*)(ws + 39741440);          // 6,144 (end 39,747,584)

    // 1. zero degree counters (own kernel — keeps runtime fillBuffer out of the graph)
    k_zero<<<NBLK, 256, 0, stream>>>(cnt);
    // 2. degree histogram + rank + W1/W2 pack
    k_count_prep<<<EB, 256, 0, stream>>>(ei, cnt, rank, W1, wh, wl, W2, wh2, wl2);
    // 3-5. exclusive scan (+dinv)
    k_scan_block<<<NBLK, 256, 0, stream>>>(cnt, rowptr, bsum, dinv);
    k_scan_bsum<<<1, 512, 0, stream>>>(bsum);
    k_scan_add<<<NBLK, 256, 0, stream>>>(rowptr, bsum);
    // 6. edge scatter (atomic-free)
    k_scatter<<<EB, 256, 0, stream>>>(ei, rowptr, rank, srcs);
    // 7. GEMM1 (counted-vmcnt pipelined MFMA, 5 blocks/CU)
    k_gemm1m<<<EB, 256, 0, stream>>>(x, (const char*)wh, (const char*)wl, dinv, h1b);
    // 8. layer-1 aggregation (+bias+relu, dinv-rescaled bf16)
    k_agg1<<<(NN * 64) / 256, 256, 0, stream>>>(rowptr, srcs, dinv, h1b, b1, hrelub);
    // 9. project to 40-dim BEFORE layer-2 aggregation (commutes with A_norm)
    k_proj<<<(NN / 16 + 3) / 4, 256, 0, stream>>>(hrelub, (const short8v*)wh2, (const short8v*)wl2, pb);
    // 10. layer-2 aggregation in 40-dim, straight to d_out
    k_agg2<<<(NN * 64) / 256, 256, 0, stream>>>(rowptr, srcs, dinv, pb, b2, out);
}